// Round 10
// baseline (439.644 us; speedup 1.0000x reference)
//
#include <hip/hip_runtime.h>
#include <hip/hip_bf16.h>
#include <math.h>

#define B_ 8
#define N_ 625
#define D_ 128
#define H_ 8
#define HD_ 16
#define MLP_ 4096
#define SCALE_ 0.25f
#define M_ 5000

typedef __attribute__((ext_vector_type(8))) short short8;
typedef __attribute__((ext_vector_type(4))) short short4v;
typedef __attribute__((ext_vector_type(4))) float f32x4;

// ---- bf16 split helpers (RNE via bit trick; inputs finite) ----
__device__ __forceinline__ unsigned short f2bf(float f) {
    unsigned u = __float_as_uint(f);
    unsigned r = (u + 0x7FFFu + ((u >> 16) & 1u)) >> 16;
    return (unsigned short)r;
}
__device__ __forceinline__ float bf2f(unsigned short h) {
    return __uint_as_float(((unsigned)h) << 16);
}

// ---- swizzled LDS byte offsets (row-major bf16 tiles, 256B rows) ----
__device__ __forceinline__ int swz256(int row, int kbyte) {
    return row * 256 + (kbyte ^ ((row & 7) << 4));
}

// ---- async global->LDS (16B/lane, wave-uniform LDS base) ----
__device__ __forceinline__ void gll16(const void* g, void* l) {
    __builtin_amdgcn_global_load_lds((const __attribute__((address_space(1))) unsigned int*)g,
                                     (__attribute__((address_space(3))) unsigned int*)l,
                                     16, 0, 0);
}

// ---- fast exact-gelu: Abramowitz-Stegun 7.1.26 erf, |err| <= 1.5e-7 ----
__device__ __forceinline__ float gelu_fast(float v) {
    float a = fabsf(v) * 0.70710678118f;
    float t = 1.0f / (1.0f + 0.3275911f * a);
    float p = t * (0.254829592f +
              t * (-0.284496736f +
              t * (1.421413741f +
              t * (-1.453152027f +
              t * 1.061405429f))));
    float erfa = 1.0f - p * __expf(-a * a);
    float phi = 0.5f * (1.0f + copysignf(erfa, v));
    return v * phi;
}

__device__ __forceinline__ float wave_reduce_sum(float v) {
#pragma unroll
    for (int off = 32; off > 0; off >>= 1) v += __shfl_xor(v, off, 64);
    return v;
}

// unpack 4 u32 (hi<<16 | lo bf16 pairs) into [hi|lo] and [hi|hi] short8 operands
__device__ __forceinline__ void unpack_fd(uint4 wv, short8* full, short8* dup) {
    short h0 = (short)(wv.x >> 16), h1 = (short)(wv.y >> 16),
          h2 = (short)(wv.z >> 16), h3 = (short)(wv.w >> 16);
    short l0 = (short)(wv.x & 0xffff), l1 = (short)(wv.y & 0xffff),
          l2 = (short)(wv.z & 0xffff), l3 = (short)(wv.w & 0xffff);
    *full = (short8){h0, h1, h2, h3, l0, l1, l2, l3};
    *dup  = (short8){h0, h1, h2, h3, h0, h1, h2, h3};
}

// ---------------- LayerNorm: one wave per row ----------------
__global__ void ln_kernel(const float* __restrict__ x, const float* __restrict__ g,
                          const float* __restrict__ b, float* __restrict__ out) {
    int wid = threadIdx.x >> 6;
    int lid = threadIdx.x & 63;
    int row = blockIdx.x * 4 + wid;
    if (row >= M_) return;
    const float* xr = x + (size_t)row * D_;
    float x0 = xr[lid], x1 = xr[lid + 64];
    float mu = wave_reduce_sum(x0 + x1) * (1.0f / D_);
    float d0 = x0 - mu, d1 = x1 - mu;
    float var = wave_reduce_sum(d0 * d0 + d1 * d1) * (1.0f / D_);
    float inv = rsqrtf(var + 1e-5f);
    float* orow = out + (size_t)row * D_;
    orow[lid]      = d0 * inv * g[lid] + b[lid];
    orow[lid + 64] = d1 * inv * g[lid + 64] + b[lid + 64];
}

// ---------------- weight transpose + bf16 hi/lo split (qkv, proj) ----------------
__global__ void tsplit(const float* __restrict__ W, unsigned short* __restrict__ Th,
                       unsigned short* __restrict__ Tl, int K, int N) {
    size_t zo = (size_t)blockIdx.z * K * N;
    __shared__ float t[32][33];
    int n0 = blockIdx.x * 32, k0 = blockIdx.y * 32;
    int c = threadIdx.x & 31, r0 = threadIdx.x >> 5;
#pragma unroll
    for (int i = 0; i < 4; i++) {
        int r = r0 + i * 8;
        t[r][c] = W[zo + (size_t)(k0 + r) * N + n0 + c];
    }
    __syncthreads();
#pragma unroll
    for (int i = 0; i < 4; i++) {
        int r = r0 + i * 8;
        float v = t[c][r];
        unsigned short h = f2bf(v);
        unsigned short l = f2bf(v - bf2f(h));
        Th[zo + (size_t)(n0 + r) * K + k0 + c] = h;
        Tl[zo + (size_t)(n0 + r) * K + k0 + c] = l;
    }
}

// ---------------- W1 prep: transpose + split + PRE-SWIZZLED k layout ----------------
__global__ void prep_w1(const float* __restrict__ W, unsigned short* __restrict__ Th,
                        unsigned short* __restrict__ Tl) {
    size_t zo = (size_t)blockIdx.z * 128 * 4096;
    size_t zo2 = (size_t)blockIdx.z * 4096 * 128;
    __shared__ float t[32][33];
    int n0 = blockIdx.x * 32, k0 = blockIdx.y * 32;
    int c = threadIdx.x & 31, r0 = threadIdx.x >> 5;
#pragma unroll
    for (int i = 0; i < 4; i++) {
        int r = r0 + i * 8;
        t[r][c] = W[zo + (size_t)(k0 + r) * 4096 + n0 + c];
    }
    __syncthreads();
#pragma unroll
    for (int i = 0; i < 4; i++) {
        int r = r0 + i * 8;
        int h = n0 + r;
        float v = t[c][r];
        unsigned short hh = f2bf(v);
        unsigned short ll = f2bf(v - bf2f(hh));
        int kk = (k0 + c) ^ ((h & 7) << 3);
        Th[zo2 + (size_t)h * 128 + kk] = hh;
        Tl[zo2 + (size_t)h * 128 + kk] = ll;
    }
}

// ---------------- W2 prep: split + kappa-permuted layout ----------------
// kappa(qh,j) = qh*4 + (j&3) + 16*(j>>2). Matches GEMM1-output A-frag k-order.
__global__ void prep_w2(const float* __restrict__ W, unsigned short* __restrict__ Th,
                        unsigned short* __restrict__ Tl) {
    size_t zo = (size_t)blockIdx.z * 4096 * 128;
    int e = blockIdx.x * 256 + threadIdx.x;
    int h = e >> 7, d = e & 127;
    float v = W[zo + (size_t)h * 128 + d];
    unsigned short hh = f2bf(v);
    unsigned short ll = f2bf(v - bf2f(hh));
    int cch = h >> 5, loc = h & 31;
    int qh = (loc & 15) >> 2;
    int j = (loc & 3) + ((loc >> 4) << 2);
    size_t off = zo + (size_t)cch * 4096 + qh * 1024 + d * 8 + j;
    Th[off] = hh;
    Tl[off] = ll;
}

// ---------------- split-bf16 MFMA GEMM: C = A(Mx128) @ B(128xNc) [+bias] [+resid] ----
template <bool BIAS, bool RESID>
__global__ __launch_bounds__(256) void gemm_mfma(
    const float* __restrict__ A, const unsigned short* __restrict__ BTh,
    const unsigned short* __restrict__ BTl, const float* __restrict__ bias,
    const float* __restrict__ resid, float* __restrict__ C, int Nc) {
    __shared__ __align__(16) char Ah[16384], Al[16384], Bh[16384], Bl[16384];
    int tid = threadIdx.x;
    int bN = blockIdx.x * 64, bM = blockIdx.y * 64;
#pragma unroll
    for (int i = 0; i < 8; i++) {
        int f = tid + i * 256;
        int row = f >> 5, k0 = (f & 31) * 4;
        int gm = bM + row;
        float4 v = make_float4(0.f, 0.f, 0.f, 0.f);
        if (gm < M_) v = *(const float4*)(A + (size_t)gm * 128 + k0);
        float vv[4] = {v.x, v.y, v.z, v.w};
        unsigned short h[4], l[4];
#pragma unroll
        for (int j = 0; j < 4; j++) { h[j] = f2bf(vv[j]); l[j] = f2bf(vv[j] - bf2f(h[j])); }
        int off = swz256(row, k0 * 2);
        *(short4v*)(Ah + off) = (short4v){(short)h[0], (short)h[1], (short)h[2], (short)h[3]};
        *(short4v*)(Al + off) = (short4v){(short)l[0], (short)l[1], (short)l[2], (short)l[3]};
    }
#pragma unroll
    for (int i = 0; i < 4; i++) {
        int c = tid + i * 256;
        int n = c >> 4, k0 = (c & 15) * 8;
        int off = swz256(n, k0 * 2);
        *(short8*)(Bh + off) = *(const short8*)(BTh + (size_t)(bN + n) * 128 + k0);
        *(short8*)(Bl + off) = *(const short8*)(BTl + (size_t)(bN + n) * 128 + k0);
    }
    __syncthreads();

    int lane = tid & 63, w = tid >> 6;
    int ln = lane & 15, qh = lane >> 4;
    int wr = w >> 1, wc = w & 1;
    f32x4 acc[2][2] = {};
#pragma unroll
    for (int ks = 0; ks < 4; ks++) {
        int kb = ks * 64 + qh * 16;
        short8 a_h[2], a_l[2], b_h[2], b_l[2];
#pragma unroll
        for (int rt = 0; rt < 2; rt++) {
            int r = wr * 32 + rt * 16 + ln;
            a_h[rt] = *(short8*)(Ah + swz256(r, kb));
            a_l[rt] = *(short8*)(Al + swz256(r, kb));
        }
#pragma unroll
        for (int ct = 0; ct < 2; ct++) {
            int n = wc * 32 + ct * 16 + ln;
            b_h[ct] = *(short8*)(Bh + swz256(n, kb));
            b_l[ct] = *(short8*)(Bl + swz256(n, kb));
        }
#pragma unroll
        for (int rt = 0; rt < 2; rt++)
#pragma unroll
            for (int ct = 0; ct < 2; ct++) {
                acc[rt][ct] = __builtin_amdgcn_mfma_f32_16x16x32_bf16(a_h[rt], b_h[ct], acc[rt][ct], 0, 0, 0);
                acc[rt][ct] = __builtin_amdgcn_mfma_f32_16x16x32_bf16(a_h[rt], b_l[ct], acc[rt][ct], 0, 0, 0);
                acc[rt][ct] = __builtin_amdgcn_mfma_f32_16x16x32_bf16(a_l[rt], b_h[ct], acc[rt][ct], 0, 0, 0);
            }
    }
#pragma unroll
    for (int rt = 0; rt < 2; rt++)
#pragma unroll
        for (int ct = 0; ct < 2; ct++) {
            int col = bN + wc * 32 + ct * 16 + ln;
            int row0 = bM + wr * 32 + rt * 16 + qh * 4;
            float bi = BIAS ? bias[col] : 0.0f;
#pragma unroll
            for (int r = 0; r < 4; r++) {
                int row = row0 + r;
                if (row < M_) {
                    float v = acc[rt][ct][r] + bi;
                    if (RESID) v += resid[(size_t)row * Nc + col];
                    C[(size_t)row * Nc + col] = v;
                }
            }
        }
}

// ---------------- MFMA flash attention (unchanged, verified) ----------------
__global__ __launch_bounds__(256) void attn_mfma(const float* __restrict__ qkv,
                                                 const int* __restrict__ mask,
                                                 float* __restrict__ o) {
    __shared__ __align__(16) unsigned int Kp[128][20];
    __shared__ __align__(16) unsigned int Vp[16][132];
    int tid = threadIdx.x;
    int lane = tid & 63, w = tid >> 6;
    int ln = lane & 15, qh = lane >> 4;
    int bh = blockIdx.y;
    int b = bh >> 3, h = bh & 7;
    int mbase = blockIdx.x * 64;

    const float* base = qkv + (size_t)b * N_ * 384;
    short8 Bqh, Bql;
    {
        int qrow = min(mbase + w * 16 + ln, N_ - 1);
        float4 f = *(const float4*)(base + (size_t)qrow * 384 + h * HD_ + qh * 4);
        float ff[4] = {f.x * SCALE_, f.y * SCALE_, f.z * SCALE_, f.w * SCALE_};
        short hs[4], ls[4];
#pragma unroll
        for (int j = 0; j < 4; j++) {
            unsigned short hh = f2bf(ff[j]);
            hs[j] = (short)hh;
            ls[j] = (short)f2bf(ff[j] - bf2f(hh));
        }
        Bqh = (short8){hs[0], hs[1], hs[2], hs[3], hs[0], hs[1], hs[2], hs[3]};
        Bql = (short8){ls[0], ls[1], ls[2], ls[3], 0, 0, 0, 0};
    }
    if (tid < 48) {
        int d = tid & 15, c = 125 + (tid >> 4);
        Vp[d][c] = 0;
    }

    float m = -3.4e38f, lsum = 0.f;
    f32x4 oacc = {0.f, 0.f, 0.f, 0.f};
    const int* mk = mask + b * 4;

    for (int ci = 0; ci < 5; ci++) {
        bool active = (ci == 4) || (mk[ci] != 0);
        if (!active) continue;
        __syncthreads();
        const float* kc = base + (size_t)ci * 125 * 384 + 128 + h * HD_;
        const float* vc = kc + 128;
        for (int e = tid; e < 500; e += 256) {
            int c = e >> 2, dq = e & 3;
            float4 kf = *(const float4*)(kc + (size_t)c * 384 + dq * 4);
            float4 vf = *(const float4*)(vc + (size_t)c * 384 + dq * 4);
            float kk[4] = {kf.x, kf.y, kf.z, kf.w};
            float vv[4] = {vf.x, vf.y, vf.z, vf.w};
            unsigned int ku[4], vu[4];
#pragma unroll
            for (int j = 0; j < 4; j++) {
                unsigned short kh = f2bf(kk[j]);
                unsigned short kl = f2bf(kk[j] - bf2f(kh));
                ku[j] = ((unsigned)kh << 16) | (unsigned)kl;
                unsigned short vh = f2bf(vv[j]);
                unsigned short vl = f2bf(vv[j] - bf2f(vh));
                vu[j] = ((unsigned)vh << 16) | (unsigned)vl;
            }
            *(uint4*)&Kp[c][dq * 4] = make_uint4(ku[0], ku[1], ku[2], ku[3]);
            Vp[dq * 4 + 0][c] = vu[0];
            Vp[dq * 4 + 1][c] = vu[1];
            Vp[dq * 4 + 2][c] = vu[2];
            Vp[dq * 4 + 3][c] = vu[3];
        }
        __syncthreads();

#pragma unroll
        for (int ct = 0; ct < 8; ct++) {
            short8 aKf, aKd;
            unpack_fd(*(const uint4*)&Kp[ct * 16 + ln][qh * 4], &aKf, &aKd);
            f32x4 s = {0.f, 0.f, 0.f, 0.f};
            s = __builtin_amdgcn_mfma_f32_16x16x32_bf16(aKf, Bqh, s, 0, 0, 0);
            s = __builtin_amdgcn_mfma_f32_16x16x32_bf16(aKd, Bql, s, 0, 0, 0);
            if (ct == 7 && qh == 3) { s[1] = -INFINITY; s[2] = -INFINITY; s[3] = -INFINITY; }
            float tmax = fmaxf(fmaxf(s[0], s[1]), fmaxf(s[2], s[3]));
            tmax = fmaxf(tmax, __shfl_xor(tmax, 16, 64));
            tmax = fmaxf(tmax, __shfl_xor(tmax, 32, 64));
            float mnew = fmaxf(m, tmax);
            float sc = __expf(m - mnew);
            m = mnew;
            lsum *= sc;
            oacc[0] *= sc; oacc[1] *= sc; oacc[2] *= sc; oacc[3] *= sc;
            float p0 = __expf(s[0] - m), p1 = __expf(s[1] - m);
            float p2 = __expf(s[2] - m), p3 = __expf(s[3] - m);
            lsum += p0 + p1 + p2 + p3;
            unsigned short h0 = f2bf(p0), h1 = f2bf(p1), h2 = f2bf(p2), h3 = f2bf(p3);
            short8 Bph = (short8){(short)h0, (short)h1, (short)h2, (short)h3,
                                  (short)h0, (short)h1, (short)h2, (short)h3};
            short8 Bpl = (short8){(short)f2bf(p0 - bf2f(h0)), (short)f2bf(p1 - bf2f(h1)),
                                  (short)f2bf(p2 - bf2f(h2)), (short)f2bf(p3 - bf2f(h3)),
                                  0, 0, 0, 0};
            short8 aVf, aVd;
            unpack_fd(*(const uint4*)&Vp[ln][ct * 16 + qh * 4], &aVf, &aVd);
            oacc = __builtin_amdgcn_mfma_f32_16x16x32_bf16(aVf, Bph, oacc, 0, 0, 0);
            oacc = __builtin_amdgcn_mfma_f32_16x16x32_bf16(aVd, Bpl, oacc, 0, 0, 0);
        }
    }

    lsum += __shfl_xor(lsum, 16, 64);
    lsum += __shfl_xor(lsum, 32, 64);
    int orow = mbase + w * 16 + ln;
    if (orow < N_) {
        float inv = 1.0f / lsum;
        float4 r = make_float4(oacc[0] * inv, oacc[1] * inv, oacc[2] * inv, oacc[3] * inv);
        *(float4*)(o + (size_t)(b * N_ + orow) * D_ + h * HD_ + qh * 4) = r;
    }
}

// ---------------- out = resid + b2 (pre-init for MLP atomic accumulation) ----------------
__global__ void init_out(const float* __restrict__ resid, const float* __restrict__ b2,
                         float* __restrict__ dest) {
    int idx = blockIdx.x * 256 + threadIdx.x;
    if (idx < M_ * D_) dest[idx] = resid[idx] + b2[idx & 127];
}

// ---------------- fused MLP v4: 8-wave blocks (128 tok), shared W chunks ----------------
// Same per-wave compute as v3 (16 tok/wave, LDS offsets are lane-only so all waves
// share the W1/W2 chunks); 8 waves double CU occupancy (2 blk/CU -> 16 waves/CU =
// 4/SIMD) at the same 66.5KB LDS, and grid halves (40 m-tiles x 16 slices = 640).
// Staging: wave w stages half of plane w>>1 (4KB each).
__global__ __launch_bounds__(512, 4) void mlp_mfma4(
    const float* __restrict__ H2, const unsigned short* __restrict__ W1sh,
    const unsigned short* __restrict__ W1sl, const float* __restrict__ b1f,
    const unsigned short* __restrict__ W2kh, const unsigned short* __restrict__ W2kl,
    float* __restrict__ dest) {
    __shared__ __align__(16) char smem[66560];  // [0,32K) buf0, [32K,64K) buf1, [64K,+1K) b1f
    int tid = threadIdx.x;
    int slice = blockIdx.x & 15;
    int mt = blockIdx.x >> 4;
    int jb = slice * 256;
    int mbase = mt * 128;
    int lane = tid & 63, w = tid >> 6;
    int ln = lane & 15, qh = lane >> 4;
    int plane = w >> 1, sub = w & 1;

    const char* pb;
    if (plane == 0)      pb = (const char*)W1sh + (size_t)jb * 256;
    else if (plane == 1) pb = (const char*)W1sl + (size_t)jb * 256;
    else if (plane == 2) pb = (const char*)W2kh + (size_t)slice * 65536;
    else                 pb = (const char*)W2kl + (size_t)slice * 65536;
    int soff = plane * 8192 + sub * 4096;   // within-buffer dest for this wave's 4KB

    int t = min(mbase + w * 16 + ln, M_ - 1);
    short8 hfh[4], hfl[4];
    {
        const float* hp = H2 + (size_t)t * 128 + qh * 8;
#pragma unroll
        for (int ks = 0; ks < 4; ks++) {
            float4 v0 = *(const float4*)(hp + ks * 32);
            float4 v1 = *(const float4*)(hp + ks * 32 + 4);
            float vv[8] = {v0.x, v0.y, v0.z, v0.w, v1.x, v1.y, v1.z, v1.w};
            short8 sh, sl;
#pragma unroll
            for (int j = 0; j < 8; j++) {
                unsigned short hh = f2bf(vv[j]);
                sh[j] = (short)hh;
                sl[j] = (short)f2bf(vv[j] - bf2f(hh));
            }
            hfh[ks] = sh; hfl[ks] = sl;
        }
    }

    {
        char* lb = smem + soff;
        const char* gb = pb + sub * 4096;
#pragma unroll
        for (int c = 0; c < 4; c++) gll16(gb + c * 1024 + lane * 16, lb + c * 1024);
        if (tid < 256) ((float*)(smem + 65536))[tid] = b1f[jb + tid];
    }
    __syncthreads();

    const float* bls = (const float*)(smem + 65536);
    f32x4 acc2[8] = {};

    for (int it = 0; it < 8; it++) {
        char* buf = smem + (it & 1) * 32768;
        if (it < 7) {
            char* lb = smem + ((it + 1) & 1) * 32768 + soff;
            const char* gb = pb + (size_t)(it + 1) * 8192 + sub * 4096;
#pragma unroll
            for (int c = 0; c < 4; c++) gll16(gb + c * 1024 + lane * 16, lb + c * 1024);
        }
        f32x4 p[2] = {};
#pragma unroll
        for (int ht = 0; ht < 2; ht++)
#pragma unroll
            for (int ks = 0; ks < 4; ks++) {
                int row = ht * 16 + ln;
                int kb = ks * 64 + qh * 16;
                short8 ah = *(short8*)(buf + swz256(row, kb));
                short8 al = *(short8*)(buf + 8192 + swz256(row, kb));
                p[ht] = __builtin_amdgcn_mfma_f32_16x16x32_bf16(ah, hfh[ks], p[ht], 0, 0, 0);
                p[ht] = __builtin_amdgcn_mfma_f32_16x16x32_bf16(ah, hfl[ks], p[ht], 0, 0, 0);
                p[ht] = __builtin_amdgcn_mfma_f32_16x16x32_bf16(al, hfh[ks], p[ht], 0, 0, 0);
            }
        short8 pah, pal;
#pragma unroll
        for (int ht = 0; ht < 2; ht++)
#pragma unroll
            for (int r = 0; r < 4; r++) {
                float bi = bls[it * 32 + ht * 16 + qh * 4 + r];
                float v = p[ht][r] + bi;
                float g = gelu_fast(v);
                unsigned short gh = f2bf(g);
                pah[ht * 4 + r] = (short)gh;
                pal[ht * 4 + r] = (short)f2bf(g - bf2f(gh));
            }
#pragma unroll
        for (int dt = 0; dt < 8; dt++) {
            int off = 16384 + qh * 2048 + (dt * 16 + ln) * 16;
            short8 bh = *(short8*)(buf + off);
            short8 bl = *(short8*)(buf + off + 8192);
            acc2[dt] = __builtin_amdgcn_mfma_f32_16x16x32_bf16(pah, bh, acc2[dt], 0, 0, 0);
            acc2[dt] = __builtin_amdgcn_mfma_f32_16x16x32_bf16(pah, bl, acc2[dt], 0, 0, 0);
            acc2[dt] = __builtin_amdgcn_mfma_f32_16x16x32_bf16(pal, bh, acc2[dt], 0, 0, 0);
        }
        __syncthreads();
    }

    int trow = mbase + w * 16 + qh * 4;
#pragma unroll
    for (int dt = 0; dt < 8; dt++) {
        int d = dt * 16 + ln;
#pragma unroll
        for (int r = 0; r < 4; r++) {
            int row = trow + r;
            if (row < M_) atomicAdd(dest + (size_t)row * 128 + d, acc2[dt][r]);
        }
    }
}

extern "C" void kernel_launch(void* const* d_in, const int* in_sizes, int n_in,
                              void* d_out, int out_size, void* d_ws, size_t ws_size,
                              hipStream_t stream) {
    const float* x     = (const float*)d_in[0];
    const int*   mask  = (const int*)d_in[1];
    const float* Wqkv  = (const float*)d_in[2];
    const float* Wproj = (const float*)d_in[3];
    const float* bproj = (const float*)d_in[4];
    const float* g1    = (const float*)d_in[5];
    const float* b1    = (const float*)d_in[6];
    const float* g2    = (const float*)d_in[7];
    const float* b2    = (const float*)d_in[8];
    const float* W1f   = (const float*)d_in[9];
    const float* b1f   = (const float*)d_in[10];
    const float* W2f   = (const float*)d_in[11];
    const float* b2f   = (const float*)d_in[12];
    float* out = (float*)d_out;
    float* ws = (float*)d_ws;

    float* xbuf   = ws;                 // 640000 f
    float* hbuf   = ws + 640000;
    float* qkvbuf = ws + 1280000;       // 1920000 f
    float* obuf   = ws + 3200000;       // 640000 f
    unsigned short* qh  = (unsigned short*)(ws + 3840000);
    unsigned short* ql  = qh + 3 * 384 * 128;
    unsigned short* phw = ql + 3 * 384 * 128;
    unsigned short* plw = phw + 3 * 128 * 128;
    unsigned short* w1h = plw + 3 * 128 * 128;   // pre-swizzled [h][k]
    unsigned short* w1l = w1h + 3 * 4096 * 128;
    unsigned short* w2h = w1l + 3 * 4096 * 128;  // kappa layout [c][qh][d][j]
    unsigned short* w2l = w2h + 3 * 128 * 4096;

    tsplit<<<dim3(12, 4, 3), 256, 0, stream>>>(Wqkv, qh, ql, 128, 384);
    tsplit<<<dim3(4, 4, 3), 256, 0, stream>>>(Wproj, phw, plw, 128, 128);
    prep_w1<<<dim3(128, 4, 3), 256, 0, stream>>>(W1f, w1h, w1l);
    prep_w2<<<dim3(2048, 1, 3), 256, 0, stream>>>(W2f, w2h, w2l);

    for (int l = 0; l < 3; l++) {
        const float* xcur = (l == 0) ? x : xbuf;
        ln_kernel<<<1250, 256, 0, stream>>>(xcur, g1 + l * D_, b1 + l * D_, hbuf);
        gemm_mfma<false, false><<<dim3(6, 79), 256, 0, stream>>>(
            hbuf, qh + (size_t)l * 384 * 128, ql + (size_t)l * 384 * 128,
            nullptr, nullptr, qkvbuf, 384);
        attn_mfma<<<dim3(10, 64), 256, 0, stream>>>(qkvbuf, mask, obuf);
        gemm_mfma<true, true><<<dim3(2, 79), 256, 0, stream>>>(
            obuf, phw + (size_t)l * 128 * 128, plw + (size_t)l * 128 * 128,
            bproj + l * D_, xcur, xbuf, 128);
        ln_kernel<<<1250, 256, 0, stream>>>(xbuf, g2 + l * D_, b2 + l * D_, hbuf);
        float* dest = (l == 2) ? out : xbuf;
        init_out<<<2500, 256, 0, stream>>>(xbuf, b2f + l * D_, dest);
        mlp_mfma4<<<640, 512, 0, stream>>>(
            hbuf, w1h + (size_t)l * 4096 * 128, w1l + (size_t)l * 4096 * 128,
            b1f + (size_t)l * MLP_,
            w2h + (size_t)l * 128 * 4096, w2l + (size_t)l * 128 * 4096, dest);
    }
}